// Round 1
// baseline (1910.377 us; speedup 1.0000x reference)
//
#include <hip/hip_runtime.h>
#include <math.h>

// Problem constants: B=64, W=48, N=64, C=64, H=64, QK=32, HOR=12
// F = 48*64*64 = 196608, O = 768

// ---- workspace layout (in floats) ----
static const size_t OFF_ENC = 0;                       // 4096*64      = 262144
static const size_t OFF_AN  = 262144;                  // 64*64*64     = 262144
static const size_t OFF_A   = 524288;                  // 12582912
static const size_t OFF_B   = 524288 + 12582912;       // 12582912
static const size_t OFF_WT  = 13107200 + 12582912;     // 61440 (conv wts transposed)
// total = 25751552 floats = ~103 MB

// ============================================================
// GRU: 8 series per block, W_hh in LDS, 48 sequential steps.
// ============================================================
__global__ __launch_bounds__(256)
void gru_kernel(const float* __restrict__ x, const float* __restrict__ wih,
                const float* __restrict__ whh, const float* __restrict__ bih,
                const float* __restrict__ bhh, float* __restrict__ enc)
{
    __shared__ float sWhh[192 * 68];   // [j][k], pad 68 (16B-aligned rows, bank spread)
    __shared__ float sH[8 * 68];       // [s][k]
    __shared__ float sGh[8 * 196];     // [s][j]
    __shared__ float sWih[192], sBih[192], sBhh[192];
    __shared__ float sX[8 * 48];

    const int tid = threadIdx.x;
    for (int idx = tid; idx < 192 * 64; idx += 256) {
        int j = idx >> 6, k = idx & 63;
        sWhh[j * 68 + k] = whh[idx];
    }
    if (tid < 192) { sWih[tid] = wih[tid]; sBih[tid] = bih[tid]; sBhh[tid] = bhh[tid]; }
    for (int idx = tid; idx < 8 * 68; idx += 256) sH[idx] = 0.0f;
    for (int idx = tid; idx < 8 * 48; idx += 256) {
        int s = idx / 48, w = idx - s * 48;
        int gs = blockIdx.x * 8 + s;
        int b = gs >> 6, n = gs & 63;
        sX[s * 48 + w] = x[(b * 48 + w) * 64 + n];
    }
    __syncthreads();

    const int s = tid & 7;
    const int g = tid >> 3;   // 0..31 : rows g*6..g*6+5, h-updates g*2, g*2+1

    for (int w = 0; w < 48; ++w) {
        float acc[6];
        #pragma unroll
        for (int r = 0; r < 6; ++r) acc[r] = sBhh[g * 6 + r];
        #pragma unroll
        for (int k = 0; k < 64; k += 4) {
            float4 hv = *(const float4*)&sH[s * 68 + k];
            #pragma unroll
            for (int r = 0; r < 6; ++r) {
                float4 wv = *(const float4*)&sWhh[(g * 6 + r) * 68 + k];
                acc[r] += hv.x * wv.x + hv.y * wv.y + hv.z * wv.z + hv.w * wv.w;
            }
        }
        #pragma unroll
        for (int r = 0; r < 6; ++r) sGh[s * 196 + g * 6 + r] = acc[r];
        __syncthreads();

        float xv = sX[s * 48 + w];
        #pragma unroll
        for (int ii = 0; ii < 2; ++ii) {
            int i = g * 2 + ii;
            float ir  = xv * sWih[i]        + sBih[i];
            float iz  = xv * sWih[64 + i]   + sBih[64 + i];
            float in_ = xv * sWih[128 + i]  + sBih[128 + i];
            float hr = sGh[s * 196 + i];
            float hz = sGh[s * 196 + 64 + i];
            float hn = sGh[s * 196 + 128 + i];
            float rg = 1.0f / (1.0f + __expf(-(ir + hr)));
            float zg = 1.0f / (1.0f + __expf(-(iz + hz)));
            float ng = tanhf(in_ + rg * hn);
            float hp = sH[s * 68 + i];
            sH[s * 68 + i] = (1.0f - zg) * ng + zg * hp;
        }
        __syncthreads();
    }
    #pragma unroll
    for (int ii = 0; ii < 2; ++ii) {
        int i = g * 2 + ii;
        enc[(size_t)(blockIdx.x * 8 + s) * 64 + i] = sH[s * 68 + i];
    }
}

// ============================================================
// Attention + softmax + gcn_norm -> Anorm[b][i][j]. 1 block per b.
// ============================================================
__global__ __launch_bounds__(256)
void attn_kernel(const float* __restrict__ enc, const float* __restrict__ wq_w,
                 const float* __restrict__ wq_b, const float* __restrict__ wk_w,
                 const float* __restrict__ wk_b, float* __restrict__ An)
{
    __shared__ float sEnc[64 * 65];      // reused as sP after Q/K phase
    __shared__ float sWq[32 * 65], sWk[32 * 65];
    __shared__ float sQb[32], sKb[32];
    __shared__ float sQ[64 * 33], sK[64 * 33];
    __shared__ float sDinv[64];
    float* sP = sEnc;

    const int tid = threadIdx.x;
    const int b = blockIdx.x;
    for (int idx = tid; idx < 4096; idx += 256) {
        int i = idx >> 6, c = idx & 63;
        sEnc[i * 65 + c] = enc[(size_t)b * 4096 + idx];
    }
    for (int idx = tid; idx < 2048; idx += 256) {
        int q = idx >> 6, c = idx & 63;
        sWq[q * 65 + c] = wq_w[idx];
        sWk[q * 65 + c] = wk_w[idx];
    }
    if (tid < 32) { sQb[tid] = wq_b[tid]; sKb[tid] = wk_b[tid]; }
    __syncthreads();
    {
        int i = tid & 63, q0 = (tid >> 6) * 8;
        float aq[8], ak[8];
        #pragma unroll
        for (int r = 0; r < 8; ++r) { aq[r] = sQb[q0 + r]; ak[r] = sKb[q0 + r]; }
        for (int c = 0; c < 64; ++c) {
            float e = sEnc[i * 65 + c];
            #pragma unroll
            for (int r = 0; r < 8; ++r) {
                aq[r] += e * sWq[(q0 + r) * 65 + c];
                ak[r] += e * sWk[(q0 + r) * 65 + c];
            }
        }
        #pragma unroll
        for (int r = 0; r < 8; ++r) { sQ[i * 33 + q0 + r] = aq[r]; sK[i * 33 + q0 + r] = ak[r]; }
    }
    __syncthreads();
    for (int r = 0; r < 16; ++r) {
        int idx = tid + 256 * r;
        int i = idx >> 6, j = idx & 63;
        float a = 0.0f;
        #pragma unroll
        for (int q = 0; q < 32; ++q) a += sQ[i * 33 + q] * sK[j * 33 + q];
        sP[i * 65 + j] = a * 0.17677669529663687f;   // 1/sqrt(32)
    }
    __syncthreads();
    if (tid < 64) {
        float mx = -1e30f;
        for (int j = 0; j < 64; ++j) mx = fmaxf(mx, sP[tid * 65 + j]);
        float sm = 0.0f;
        for (int j = 0; j < 64; ++j) { float e = __expf(sP[tid * 65 + j] - mx); sP[tid * 65 + j] = e; sm += e; }
        float inv = 1.0f / sm;
        for (int j = 0; j < 64; ++j) sP[tid * 65 + j] *= inv;
    }
    __syncthreads();
    if (tid < 64) {
        float d = 0.0f;
        for (int i = 0; i < 64; ++i) d += sP[i * 65 + tid];   // column sums (deg)
        sDinv[tid] = rsqrtf(d);
    }
    __syncthreads();
    for (int r = 0; r < 16; ++r) {
        int idx = tid + 256 * r;
        int i = idx >> 6, j = idx & 63;
        An[(size_t)b * 4096 + idx] = sDinv[i] * sP[i * 65 + j] * sDinv[j];
    }
}

// ============================================================
// Fused GCN linear (C x C) + node aggregation (Anorm) per (b,t).
// MODE 0: h_in built from x*emb_w+emb_b on the fly. MODE 1: from buffer.
// ============================================================
template<int MODE>
__global__ __launch_bounds__(256)
void linagg_kernel(const float* __restrict__ hin, const float* __restrict__ x,
                   const float* __restrict__ emb_w, const float* __restrict__ emb_b,
                   const float* __restrict__ gw, const float* __restrict__ gb,
                   const float* __restrict__ An, float* __restrict__ outp)
{
    __shared__ float sHT[64 * 68];   // h^T: [c][i]
    __shared__ float sU[64 * 68];    // phase1: gw natural [c'][c] (stride 68); phase2: Anorm [i][j] (stride 64)
    __shared__ float sGT[64 * 68];   // g^T: [c'][i]
    __shared__ float sGb[64];
    __shared__ float sXr[64];

    const int tid = threadIdx.x;
    const int bt = blockIdx.x;              // b*48 + t
    const int b = bt / 48;

    if (tid < 64) sGb[tid] = gb[tid];
    if (MODE == 0) {
        if (tid < 64) sXr[tid] = x[(size_t)bt * 64 + tid];
    } else {
        for (int idx = tid; idx < 4096; idx += 256) {
            int i = idx >> 6, c = idx & 63;
            sHT[c * 68 + i] = hin[(size_t)bt * 4096 + idx];
        }
    }
    for (int idx = tid; idx < 4096; idx += 256) {
        int cp = idx >> 6, c = idx & 63;
        sU[cp * 68 + c] = gw[idx];          // natural copy [c'][c]
    }
    __syncthreads();
    if (MODE == 0) {
        for (int idx = tid; idx < 4096; idx += 256) {
            int c = idx >> 6, i = idx & 63;
            sHT[c * 68 + i] = sXr[i] * emb_w[c] + emb_b[c];
        }
        __syncthreads();
    }

    const int lo = tid & 15, hi = tid >> 4;  // 16 x 16 thread tiles
    // -------- phase 1: g[i][c'] = sum_c h[i][c]*gw[c'][c], stored transposed --------
    {
        const int i0 = lo * 4, c0 = hi * 4;
        float a[4][4] = {};
        for (int c4 = 0; c4 < 64; c4 += 4) {
            float4 w0 = *(const float4*)&sU[(c0 + 0) * 68 + c4];
            float4 w1 = *(const float4*)&sU[(c0 + 1) * 68 + c4];
            float4 w2 = *(const float4*)&sU[(c0 + 2) * 68 + c4];
            float4 w3 = *(const float4*)&sU[(c0 + 3) * 68 + c4];
            float4 h0 = *(const float4*)&sHT[(c4 + 0) * 68 + i0];
            float4 h1 = *(const float4*)&sHT[(c4 + 1) * 68 + i0];
            float4 h2 = *(const float4*)&sHT[(c4 + 2) * 68 + i0];
            float4 h3 = *(const float4*)&sHT[(c4 + 3) * 68 + i0];
            float wc[4][4] = {{w0.x,w0.y,w0.z,w0.w},{w1.x,w1.y,w1.z,w1.w},
                              {w2.x,w2.y,w2.z,w2.w},{w3.x,w3.y,w3.z,w3.w}};
            float hc[4][4] = {{h0.x,h0.y,h0.z,h0.w},{h1.x,h1.y,h1.z,h1.w},
                              {h2.x,h2.y,h2.z,h2.w},{h3.x,h3.y,h3.z,h3.w}};
            #pragma unroll
            for (int r = 0; r < 4; ++r)
                #pragma unroll
                for (int ii = 0; ii < 4; ++ii)
                    #pragma unroll
                    for (int cc = 0; cc < 4; ++cc)
                        a[ii][cc] += hc[r][ii] * wc[cc][r];
        }
        #pragma unroll
        for (int cc = 0; cc < 4; ++cc)
            *(float4*)&sGT[(c0 + cc) * 68 + i0] =
                make_float4(a[0][cc], a[1][cc], a[2][cc], a[3][cc]);
    }
    __syncthreads();
    // reload sU as Anorm (stride 64)
    for (int idx = tid; idx < 4096; idx += 256)
        sU[idx] = An[(size_t)b * 4096 + idx];
    __syncthreads();
    // -------- phase 2: out[j][c'] = sum_i An[i][j]*g[i][c'] + gb --------
    {
        const int j0 = lo * 4, c0 = hi * 4;
        float o[4][4] = {};
        for (int i4 = 0; i4 < 64; i4 += 4) {
            float4 g0 = *(const float4*)&sGT[(c0 + 0) * 68 + i4];
            float4 g1 = *(const float4*)&sGT[(c0 + 1) * 68 + i4];
            float4 g2 = *(const float4*)&sGT[(c0 + 2) * 68 + i4];
            float4 g3 = *(const float4*)&sGT[(c0 + 3) * 68 + i4];
            float4 a0 = *(const float4*)&sU[(i4 + 0) * 64 + j0];
            float4 a1 = *(const float4*)&sU[(i4 + 1) * 64 + j0];
            float4 a2 = *(const float4*)&sU[(i4 + 2) * 64 + j0];
            float4 a3 = *(const float4*)&sU[(i4 + 3) * 64 + j0];
            float gc[4][4] = {{g0.x,g0.y,g0.z,g0.w},{g1.x,g1.y,g1.z,g1.w},
                              {g2.x,g2.y,g2.z,g2.w},{g3.x,g3.y,g3.z,g3.w}};
            float ac[4][4] = {{a0.x,a0.y,a0.z,a0.w},{a1.x,a1.y,a1.z,a1.w},
                              {a2.x,a2.y,a2.z,a2.w},{a3.x,a3.y,a3.z,a3.w}};
            #pragma unroll
            for (int r = 0; r < 4; ++r)
                #pragma unroll
                for (int jj = 0; jj < 4; ++jj)
                    #pragma unroll
                    for (int cc = 0; cc < 4; ++cc)
                        o[jj][cc] += ac[r][jj] * gc[cc][r];
        }
        size_t base = (size_t)bt * 4096;
        #pragma unroll
        for (int jj = 0; jj < 4; ++jj) {
            float4 v = make_float4(o[jj][0] + sGb[c0 + 0], o[jj][1] + sGb[c0 + 1],
                                   o[jj][2] + sGb[c0 + 2], o[jj][3] + sGb[c0 + 3]);
            *(float4*)&outp[base + (size_t)(j0 + jj) * 64 + c0] = v;
        }
    }
}

// ============================================================
// Conv1d over W (kernel K, same-pad) + bias + leaky_relu(0.01).
// 4 nodes per block; input tile in LDS; weights from L2 (transposed [ci][d][co]).
// ============================================================
template<int K>
__global__ __launch_bounds__(256)
void conv_kernel(const float* __restrict__ in, const float* __restrict__ wt,
                 const float* __restrict__ cb, float* __restrict__ outp)
{
    __shared__ float sIn[4 * 64 * 55];
    const int tid = threadIdx.x;
    const int b = blockIdx.x >> 4;
    const int n0 = (blockIdx.x & 15) * 4;
    const int PAD = K / 2;
    for (int idx = tid; idx < 4 * 64 * 55; idx += 256) sIn[idx] = 0.0f;
    __syncthreads();
    {
        const int ci = tid & 63;
        const int r0 = tid >> 6;
        for (int rr = 0; rr < 48; ++rr) {
            int rowid = r0 + 4 * rr;
            int nn = rowid & 3, t = rowid >> 2;
            sIn[(nn * 64 + ci) * 55 + PAD + t] =
                in[(((size_t)b * 48 + t) * 64 + n0 + nn) * 64 + ci];
        }
    }
    __syncthreads();
    const int co = tid & 63;
    const int q = tid >> 6;    // 4 t-quarters of 12
    float bias = cb[co];
    float acc[4][12] = {};
    for (int ci = 0; ci < 64; ++ci) {
        float wreg[K];
        #pragma unroll
        for (int d = 0; d < K; ++d) wreg[d] = wt[(ci * K + d) * 64 + co];
        #pragma unroll
        for (int nn = 0; nn < 4; ++nn) {
            float iw[12 + K - 1];
            #pragma unroll
            for (int u = 0; u < 12 + K - 1; ++u)
                iw[u] = sIn[(nn * 64 + ci) * 55 + q * 12 + u];
            #pragma unroll
            for (int dt = 0; dt < 12; ++dt)
                #pragma unroll
                for (int d = 0; d < K; ++d)
                    acc[nn][dt] += wreg[d] * iw[dt + d];
        }
    }
    for (int nn = 0; nn < 4; ++nn)
        for (int dt = 0; dt < 12; ++dt) {
            float v = acc[nn][dt] + bias;
            v = v > 0.0f ? v : 0.01f * v;
            outp[(((size_t)b * 48 + q * 12 + dt) * 64 + n0 + nn) * 64 + co] = v;
        }
}

// ============================================================
// Conv-weight transpose: wt[ci*K+d][co] = w[co][ci][d]
// ============================================================
__global__ __launch_bounds__(256)
void prep_wt_kernel(const float* __restrict__ w0, const float* __restrict__ w1,
                    const float* __restrict__ w2, float* __restrict__ wt)
{
    int idx = blockIdx.x * 256 + threadIdx.x;
    if (idx >= 61440) return;
    if (idx < 12288) {
        int rel = idx, co = rel & 63, r2 = rel >> 6;
        int d = r2 % 3, ci = r2 / 3;
        wt[rel] = w0[(co * 64 + ci) * 3 + d];
    } else if (idx < 32768) {
        int rel = idx - 12288, co = rel & 63, r2 = rel >> 6;
        int d = r2 % 5, ci = r2 / 5;
        wt[12288 + rel] = w1[(co * 64 + ci) * 5 + d];
    } else {
        int rel = idx - 32768, co = rel & 63, r2 = rel >> 6;
        int d = r2 % 7, ci = r2 / 7;
        wt[32768 + rel] = w2[(co * 64 + ci) * 7 + d];
    }
}

// ============================================================
// Final linear: out[64][768] = h3[64][196608] @ lw^T + lb
// 4 o-tiles (192) x 64 K-chunks (3072) = 256 blocks (1/CU), atomic epilogue.
// ============================================================
__global__ __launch_bounds__(256)
void out_init_kernel(const float* __restrict__ lb, float* __restrict__ outp)
{
    int idx = blockIdx.x * 256 + threadIdx.x;
    if (idx < 64 * 768) outp[idx] = lb[idx % 768];
}

__global__ __launch_bounds__(256)
void final_kernel(const float* __restrict__ hf, const float* __restrict__ lw,
                  float* __restrict__ outp)
{
    __shared__ float sW[32 * 196];   // [k][o] o-tile 192 (+4 pad)
    __shared__ float sA[32 * 72];    // [k][b]
    const int tid = threadIdx.x;
    const int kc = blockIdx.x & 63;
    const int ot = blockIdx.x >> 6;
    const int o0 = ot * 192;
    const int kk4 = tid & 7;          // k-offset/4 within 32-k chunk
    const int rowl = tid >> 3;        // 0..31
    const int o_loc = (tid & 15) * 12;
    const int b0 = (tid >> 4) * 4;
    float acc[12][4] = {};
    for (int ks = 0; ks < 96; ++ks) {
        const size_t k0 = (size_t)kc * 3072 + ks * 32;
        #pragma unroll
        for (int r = 0; r < 6; ++r) {
            int row = rowl + 32 * r;   // 0..191
            float4 wv = *(const float4*)&lw[(size_t)(o0 + row) * 196608 + k0 + kk4 * 4];
            sW[(kk4 * 4 + 0) * 196 + row] = wv.x;
            sW[(kk4 * 4 + 1) * 196 + row] = wv.y;
            sW[(kk4 * 4 + 2) * 196 + row] = wv.z;
            sW[(kk4 * 4 + 3) * 196 + row] = wv.w;
        }
        #pragma unroll
        for (int r = 0; r < 2; ++r) {
            int bb = rowl + 32 * r;    // 0..63
            float4 av = *(const float4*)&hf[(size_t)bb * 196608 + k0 + kk4 * 4];
            sA[(kk4 * 4 + 0) * 72 + bb] = av.x;
            sA[(kk4 * 4 + 1) * 72 + bb] = av.y;
            sA[(kk4 * 4 + 2) * 72 + bb] = av.z;
            sA[(kk4 * 4 + 3) * 72 + bb] = av.w;
        }
        __syncthreads();
        for (int k = 0; k < 32; ++k) {
            float4 a = *(const float4*)&sA[k * 72 + b0];
            float4 w0 = *(const float4*)&sW[k * 196 + o_loc];
            float4 w1 = *(const float4*)&sW[k * 196 + o_loc + 4];
            float4 w2 = *(const float4*)&sW[k * 196 + o_loc + 8];
            float av[4] = {a.x, a.y, a.z, a.w};
            float wv[12] = {w0.x,w0.y,w0.z,w0.w,w1.x,w1.y,w1.z,w1.w,w2.x,w2.y,w2.z,w2.w};
            #pragma unroll
            for (int oo = 0; oo < 12; ++oo)
                #pragma unroll
                for (int bi = 0; bi < 4; ++bi)
                    acc[oo][bi] += wv[oo] * av[bi];
        }
        __syncthreads();
    }
    #pragma unroll
    for (int oo = 0; oo < 12; ++oo)
        #pragma unroll
        for (int bi = 0; bi < 4; ++bi)
            atomicAdd(&outp[(size_t)(b0 + bi) * 768 + o0 + o_loc + oo], acc[oo][bi]);
}

// ============================================================
extern "C" void kernel_launch(void* const* d_in, const int* in_sizes, int n_in,
                              void* d_out, int out_size, void* d_ws, size_t ws_size,
                              hipStream_t stream)
{
    const float* x     = (const float*)d_in[0];
    const float* wih   = (const float*)d_in[1];
    const float* whh   = (const float*)d_in[2];
    const float* bih   = (const float*)d_in[3];
    const float* bhh   = (const float*)d_in[4];
    const float* wq_w  = (const float*)d_in[5];
    const float* wq_b  = (const float*)d_in[6];
    const float* wk_w  = (const float*)d_in[7];
    const float* wk_b  = (const float*)d_in[8];
    const float* emb_w = (const float*)d_in[9];
    const float* emb_b = (const float*)d_in[10];
    const float* gcn_w[3] = {(const float*)d_in[11], (const float*)d_in[15], (const float*)d_in[19]};
    const float* gcn_b[3] = {(const float*)d_in[12], (const float*)d_in[16], (const float*)d_in[20]};
    const float* cv_w[3]  = {(const float*)d_in[13], (const float*)d_in[17], (const float*)d_in[21]};
    const float* cv_b[3]  = {(const float*)d_in[14], (const float*)d_in[18], (const float*)d_in[22]};
    const float* lw = (const float*)d_in[23];
    const float* lb = (const float*)d_in[24];

    float* out  = (float*)d_out;
    float* ws   = (float*)d_ws;
    float* enc  = ws + OFF_ENC;
    float* An   = ws + OFF_AN;
    float* bufA = ws + OFF_A;
    float* bufB = ws + OFF_B;
    float* wt   = ws + OFF_WT;

    prep_wt_kernel<<<240, 256, 0, stream>>>(cv_w[0], cv_w[1], cv_w[2], wt);
    gru_kernel<<<512, 256, 0, stream>>>(x, wih, whh, bih, bhh, enc);
    attn_kernel<<<64, 256, 0, stream>>>(enc, wq_w, wq_b, wk_w, wk_b, An);

    linagg_kernel<0><<<3072, 256, 0, stream>>>(nullptr, x, emb_w, emb_b,
                                               gcn_w[0], gcn_b[0], An, bufA);
    conv_kernel<3><<<1024, 256, 0, stream>>>(bufA, wt, cv_b[0], bufB);

    linagg_kernel<1><<<3072, 256, 0, stream>>>(bufB, x, emb_w, emb_b,
                                               gcn_w[1], gcn_b[1], An, bufA);
    conv_kernel<5><<<1024, 256, 0, stream>>>(bufA, wt + 12288, cv_b[1], bufB);

    linagg_kernel<1><<<3072, 256, 0, stream>>>(bufB, x, emb_w, emb_b,
                                               gcn_w[2], gcn_b[2], An, bufA);
    conv_kernel<7><<<1024, 256, 0, stream>>>(bufA, wt + 32768, cv_b[2], bufB);

    out_init_kernel<<<192, 256, 0, stream>>>(lb, out);
    final_kernel<<<256, 256, 0, stream>>>(bufB, lw, out);
}

// Round 2
// 1605.495 us; speedup vs baseline: 1.1899x; 1.1899x over previous
//
#include <hip/hip_runtime.h>
#include <math.h>

// Problem constants: B=64, W=48, N=64, C=64, H=64, QK=32, HOR=12
// F = 48*64*64 = 196608, O = 768

// ---- workspace layout (in floats) ----
static const size_t OFF_ENC = 0;                       // 4096*64      = 262144
static const size_t OFF_AN  = 262144;                  // 64*64*64     = 262144
static const size_t OFF_A   = 524288;                  // 12582912  (also reused as final partials: 1024*12288)
static const size_t OFF_B   = 524288 + 12582912;       // 12582912
static const size_t OFF_WT  = 13107200 + 12582912;     // 61440 (conv wts transposed)

// ============================================================
// GRU: 8 series per block, W_hh in LDS, 48 sequential steps.
// ============================================================
__global__ __launch_bounds__(256)
void gru_kernel(const float* __restrict__ x, const float* __restrict__ wih,
                const float* __restrict__ whh, const float* __restrict__ bih,
                const float* __restrict__ bhh, float* __restrict__ enc)
{
    __shared__ float sWhh[192 * 68];
    __shared__ float sH[8 * 68];
    __shared__ float sGh[8 * 196];
    __shared__ float sWih[192], sBih[192], sBhh[192];
    __shared__ float sX[8 * 48];

    const int tid = threadIdx.x;
    for (int idx = tid; idx < 192 * 64; idx += 256) {
        int j = idx >> 6, k = idx & 63;
        sWhh[j * 68 + k] = whh[idx];
    }
    if (tid < 192) { sWih[tid] = wih[tid]; sBih[tid] = bih[tid]; sBhh[tid] = bhh[tid]; }
    for (int idx = tid; idx < 8 * 68; idx += 256) sH[idx] = 0.0f;
    for (int idx = tid; idx < 8 * 48; idx += 256) {
        int s = idx / 48, w = idx - s * 48;
        int gs = blockIdx.x * 8 + s;
        int b = gs >> 6, n = gs & 63;
        sX[s * 48 + w] = x[(b * 48 + w) * 64 + n];
    }
    __syncthreads();

    const int s = tid & 7;
    const int g = tid >> 3;

    for (int w = 0; w < 48; ++w) {
        float acc[6];
        #pragma unroll
        for (int r = 0; r < 6; ++r) acc[r] = sBhh[g * 6 + r];
        #pragma unroll
        for (int k = 0; k < 64; k += 4) {
            float4 hv = *(const float4*)&sH[s * 68 + k];
            #pragma unroll
            for (int r = 0; r < 6; ++r) {
                float4 wv = *(const float4*)&sWhh[(g * 6 + r) * 68 + k];
                acc[r] += hv.x * wv.x + hv.y * wv.y + hv.z * wv.z + hv.w * wv.w;
            }
        }
        #pragma unroll
        for (int r = 0; r < 6; ++r) sGh[s * 196 + g * 6 + r] = acc[r];
        __syncthreads();

        float xv = sX[s * 48 + w];
        #pragma unroll
        for (int ii = 0; ii < 2; ++ii) {
            int i = g * 2 + ii;
            float ir  = xv * sWih[i]        + sBih[i];
            float iz  = xv * sWih[64 + i]   + sBih[64 + i];
            float in_ = xv * sWih[128 + i]  + sBih[128 + i];
            float hr = sGh[s * 196 + i];
            float hz = sGh[s * 196 + 64 + i];
            float hn = sGh[s * 196 + 128 + i];
            float rg = 1.0f / (1.0f + __expf(-(ir + hr)));
            float zg = 1.0f / (1.0f + __expf(-(iz + hz)));
            float ng = tanhf(in_ + rg * hn);
            float hp = sH[s * 68 + i];
            sH[s * 68 + i] = (1.0f - zg) * ng + zg * hp;
        }
        __syncthreads();
    }
    #pragma unroll
    for (int ii = 0; ii < 2; ++ii) {
        int i = g * 2 + ii;
        enc[(size_t)(blockIdx.x * 8 + s) * 64 + i] = sH[s * 68 + i];
    }
}

// ============================================================
// Attention + softmax + gcn_norm -> Anorm[b][i][j]. 1 block per b.
// ============================================================
__global__ __launch_bounds__(256)
void attn_kernel(const float* __restrict__ enc, const float* __restrict__ wq_w,
                 const float* __restrict__ wq_b, const float* __restrict__ wk_w,
                 const float* __restrict__ wk_b, float* __restrict__ An)
{
    __shared__ float sEnc[64 * 65];
    __shared__ float sWq[32 * 65], sWk[32 * 65];
    __shared__ float sQb[32], sKb[32];
    __shared__ float sQ[64 * 33], sK[64 * 33];
    __shared__ float sDinv[64];
    float* sP = sEnc;

    const int tid = threadIdx.x;
    const int b = blockIdx.x;
    for (int idx = tid; idx < 4096; idx += 256) {
        int i = idx >> 6, c = idx & 63;
        sEnc[i * 65 + c] = enc[(size_t)b * 4096 + idx];
    }
    for (int idx = tid; idx < 2048; idx += 256) {
        int q = idx >> 6, c = idx & 63;
        sWq[q * 65 + c] = wq_w[idx];
        sWk[q * 65 + c] = wk_w[idx];
    }
    if (tid < 32) { sQb[tid] = wq_b[tid]; sKb[tid] = wk_b[tid]; }
    __syncthreads();
    {
        int i = tid & 63, q0 = (tid >> 6) * 8;
        float aq[8], ak[8];
        #pragma unroll
        for (int r = 0; r < 8; ++r) { aq[r] = sQb[q0 + r]; ak[r] = sKb[q0 + r]; }
        for (int c = 0; c < 64; ++c) {
            float e = sEnc[i * 65 + c];
            #pragma unroll
            for (int r = 0; r < 8; ++r) {
                aq[r] += e * sWq[(q0 + r) * 65 + c];
                ak[r] += e * sWk[(q0 + r) * 65 + c];
            }
        }
        #pragma unroll
        for (int r = 0; r < 8; ++r) { sQ[i * 33 + q0 + r] = aq[r]; sK[i * 33 + q0 + r] = ak[r]; }
    }
    __syncthreads();
    for (int r = 0; r < 16; ++r) {
        int idx = tid + 256 * r;
        int i = idx >> 6, j = idx & 63;
        float a = 0.0f;
        #pragma unroll
        for (int q = 0; q < 32; ++q) a += sQ[i * 33 + q] * sK[j * 33 + q];
        sP[i * 65 + j] = a * 0.17677669529663687f;
    }
    __syncthreads();
    if (tid < 64) {
        float mx = -1e30f;
        for (int j = 0; j < 64; ++j) mx = fmaxf(mx, sP[tid * 65 + j]);
        float sm = 0.0f;
        for (int j = 0; j < 64; ++j) { float e = __expf(sP[tid * 65 + j] - mx); sP[tid * 65 + j] = e; sm += e; }
        float inv = 1.0f / sm;
        for (int j = 0; j < 64; ++j) sP[tid * 65 + j] *= inv;
    }
    __syncthreads();
    if (tid < 64) {
        float d = 0.0f;
        for (int i = 0; i < 64; ++i) d += sP[i * 65 + tid];
        sDinv[tid] = rsqrtf(d);
    }
    __syncthreads();
    for (int r = 0; r < 16; ++r) {
        int idx = tid + 256 * r;
        int i = idx >> 6, j = idx & 63;
        An[(size_t)b * 4096 + idx] = sDinv[i] * sP[i * 65 + j] * sDinv[j];
    }
}

// ============================================================
// Fused GCN linear + node aggregation per (b,t).
// v2: gw and An read straight from global (L2-hot, 16KB each);
// LDS = sHT + sGT only (35KB) -> 4 blocks/CU.
// ============================================================
template<int MODE>
__global__ __launch_bounds__(256, 4)
void linagg_kernel(const float* __restrict__ hin, const float* __restrict__ x,
                   const float* __restrict__ emb_w, const float* __restrict__ emb_b,
                   const float* __restrict__ gw, const float* __restrict__ gb,
                   const float* __restrict__ An, float* __restrict__ outp)
{
    __shared__ float sHT[64 * 68];   // h^T: [c][i]
    __shared__ float sGT[64 * 68];   // g^T: [c'][i]
    __shared__ float sGb[64];
    __shared__ float sXr[64];

    const int tid = threadIdx.x;
    const int bt = blockIdx.x;
    const int b = bt / 48;

    if (tid < 64) sGb[tid] = gb[tid];
    if (MODE == 0) {
        if (tid < 64) sXr[tid] = x[(size_t)bt * 64 + tid];
        __syncthreads();
        for (int idx = tid; idx < 4096; idx += 256) {
            int c = idx >> 6, i = idx & 63;
            sHT[c * 68 + i] = sXr[i] * emb_w[c] + emb_b[c];
        }
    } else {
        for (int idx = tid; idx < 4096; idx += 256) {
            int i = idx >> 6, c = idx & 63;
            sHT[c * 68 + i] = hin[(size_t)bt * 4096 + idx];
        }
    }
    __syncthreads();

    const int lo = tid & 15, hi = tid >> 4;
    // -------- phase 1: g[i][c'] = sum_c h[i][c]*gw[c'][c], stored transposed --------
    {
        const int i0 = lo * 4, c0 = hi * 4;
        float a[4][4] = {};
        for (int c4 = 0; c4 < 64; c4 += 4) {
            float4 w0 = *(const float4*)&gw[(c0 + 0) * 64 + c4];
            float4 w1 = *(const float4*)&gw[(c0 + 1) * 64 + c4];
            float4 w2 = *(const float4*)&gw[(c0 + 2) * 64 + c4];
            float4 w3 = *(const float4*)&gw[(c0 + 3) * 64 + c4];
            float4 h0 = *(const float4*)&sHT[(c4 + 0) * 68 + i0];
            float4 h1 = *(const float4*)&sHT[(c4 + 1) * 68 + i0];
            float4 h2 = *(const float4*)&sHT[(c4 + 2) * 68 + i0];
            float4 h3 = *(const float4*)&sHT[(c4 + 3) * 68 + i0];
            float wc[4][4] = {{w0.x,w0.y,w0.z,w0.w},{w1.x,w1.y,w1.z,w1.w},
                              {w2.x,w2.y,w2.z,w2.w},{w3.x,w3.y,w3.z,w3.w}};
            float hc[4][4] = {{h0.x,h0.y,h0.z,h0.w},{h1.x,h1.y,h1.z,h1.w},
                              {h2.x,h2.y,h2.z,h2.w},{h3.x,h3.y,h3.z,h3.w}};
            #pragma unroll
            for (int r = 0; r < 4; ++r)
                #pragma unroll
                for (int ii = 0; ii < 4; ++ii)
                    #pragma unroll
                    for (int cc = 0; cc < 4; ++cc)
                        a[ii][cc] += hc[r][ii] * wc[cc][r];
        }
        #pragma unroll
        for (int cc = 0; cc < 4; ++cc)
            *(float4*)&sGT[(c0 + cc) * 68 + i0] =
                make_float4(a[0][cc], a[1][cc], a[2][cc], a[3][cc]);
    }
    __syncthreads();
    // -------- phase 2: out[j][c'] = sum_i An[i][j]*g[i][c'] + gb --------
    {
        const int j0 = lo * 4, c0 = hi * 4;
        const float* Ab = An + (size_t)b * 4096;
        float o[4][4] = {};
        for (int i4 = 0; i4 < 64; i4 += 4) {
            float4 g0 = *(const float4*)&sGT[(c0 + 0) * 68 + i4];
            float4 g1 = *(const float4*)&sGT[(c0 + 1) * 68 + i4];
            float4 g2 = *(const float4*)&sGT[(c0 + 2) * 68 + i4];
            float4 g3 = *(const float4*)&sGT[(c0 + 3) * 68 + i4];
            float4 a0 = *(const float4*)&Ab[(i4 + 0) * 64 + j0];
            float4 a1 = *(const float4*)&Ab[(i4 + 1) * 64 + j0];
            float4 a2 = *(const float4*)&Ab[(i4 + 2) * 64 + j0];
            float4 a3 = *(const float4*)&Ab[(i4 + 3) * 64 + j0];
            float gc[4][4] = {{g0.x,g0.y,g0.z,g0.w},{g1.x,g1.y,g1.z,g1.w},
                              {g2.x,g2.y,g2.z,g2.w},{g3.x,g3.y,g3.z,g3.w}};
            float ac[4][4] = {{a0.x,a0.y,a0.z,a0.w},{a1.x,a1.y,a1.z,a1.w},
                              {a2.x,a2.y,a2.z,a2.w},{a3.x,a3.y,a3.z,a3.w}};
            #pragma unroll
            for (int r = 0; r < 4; ++r)
                #pragma unroll
                for (int jj = 0; jj < 4; ++jj)
                    #pragma unroll
                    for (int cc = 0; cc < 4; ++cc)
                        o[jj][cc] += ac[r][jj] * gc[cc][r];
        }
        size_t base = (size_t)bt * 4096;
        #pragma unroll
        for (int jj = 0; jj < 4; ++jj) {
            float4 v = make_float4(o[jj][0] + sGb[c0 + 0], o[jj][1] + sGb[c0 + 1],
                                   o[jj][2] + sGb[c0 + 2], o[jj][3] + sGb[c0 + 3]);
            *(float4*)&outp[base + (size_t)(j0 + jj) * 64 + c0] = v;
        }
    }
}

// ============================================================
// Conv1d over W + bias + leaky_relu. v2: 2 nodes/block (LDS 28KB -> 5 blocks/CU).
// ============================================================
template<int K>
__global__ __launch_bounds__(256, 4)
void conv_kernel(const float* __restrict__ in, const float* __restrict__ wt,
                 const float* __restrict__ cb, float* __restrict__ outp)
{
    __shared__ float sIn[2 * 64 * 55];
    const int tid = threadIdx.x;
    const int b = blockIdx.x >> 5;
    const int n0 = (blockIdx.x & 31) * 2;
    const int PAD = K / 2;
    for (int idx = tid; idx < 2 * 64 * 55; idx += 256) sIn[idx] = 0.0f;
    __syncthreads();
    {
        const int ci = tid & 63;
        const int r0 = tid >> 6;
        for (int rr = 0; rr < 24; ++rr) {
            int rowid = r0 + 4 * rr;          // 0..95
            int nn = rowid & 1, t = rowid >> 1;
            sIn[(nn * 64 + ci) * 55 + PAD + t] =
                in[(((size_t)b * 48 + t) * 64 + n0 + nn) * 64 + ci];
        }
    }
    __syncthreads();
    const int co = tid & 63;
    const int q = tid >> 6;
    float bias = cb[co];
    float acc[2][12] = {};
    for (int ci = 0; ci < 64; ++ci) {
        float wreg[K];
        #pragma unroll
        for (int d = 0; d < K; ++d) wreg[d] = wt[(ci * K + d) * 64 + co];
        #pragma unroll
        for (int nn = 0; nn < 2; ++nn) {
            float iw[12 + K - 1];
            #pragma unroll
            for (int u = 0; u < 12 + K - 1; ++u)
                iw[u] = sIn[(nn * 64 + ci) * 55 + q * 12 + u];
            #pragma unroll
            for (int dt = 0; dt < 12; ++dt)
                #pragma unroll
                for (int d = 0; d < K; ++d)
                    acc[nn][dt] += wreg[d] * iw[dt + d];
        }
    }
    for (int nn = 0; nn < 2; ++nn)
        for (int dt = 0; dt < 12; ++dt) {
            float v = acc[nn][dt] + bias;
            v = v > 0.0f ? v : 0.01f * v;
            outp[(((size_t)b * 48 + q * 12 + dt) * 64 + n0 + nn) * 64 + co] = v;
        }
}

// ============================================================
// Conv-weight transpose: wt[ci*K+d][co] = w[co][ci][d]
// ============================================================
__global__ __launch_bounds__(256)
void prep_wt_kernel(const float* __restrict__ w0, const float* __restrict__ w1,
                    const float* __restrict__ w2, float* __restrict__ wt)
{
    int idx = blockIdx.x * 256 + threadIdx.x;
    if (idx >= 61440) return;
    if (idx < 12288) {
        int rel = idx, co = rel & 63, r2 = rel >> 6;
        int d = r2 % 3, ci = r2 / 3;
        wt[rel] = w0[(co * 64 + ci) * 3 + d];
    } else if (idx < 32768) {
        int rel = idx - 12288, co = rel & 63, r2 = rel >> 6;
        int d = r2 % 5, ci = r2 / 5;
        wt[12288 + rel] = w1[(co * 64 + ci) * 5 + d];
    } else {
        int rel = idx - 32768, co = rel & 63, r2 = rel >> 6;
        int d = r2 % 7, ci = r2 / 7;
        wt[32768 + rel] = w2[(co * 64 + ci) * 7 + d];
    }
}

// ============================================================
// Final linear. v2: 1024 blocks (256 k-chunks x 4 o-tiles, 4 blocks/CU),
// partial sums into workspace (no atomics), sA stride 68 (was 72: 8-way conflicts).
// part layout: part[bid][b][192]  (bid = kc*4 + ot)
// ============================================================
__global__ __launch_bounds__(256, 4)
void final_kernel(const float* __restrict__ hf, const float* __restrict__ lw,
                  float* __restrict__ part)
{
    __shared__ float sW[32 * 196];   // [k][o-tile 192 +4]
    __shared__ float sA[32 * 68];    // [k][b +4]
    const int tid = threadIdx.x;
    const int kc = blockIdx.x >> 2;    // 0..255
    const int ot = blockIdx.x & 3;     // 0..3
    const int o0 = ot * 192;
    const int kk4 = tid & 7;
    const int rowl = tid >> 3;
    const int o_loc = (tid & 15) * 12;
    const int b0 = (tid >> 4) * 4;
    float acc[12][4] = {};
    for (int ks = 0; ks < 24; ++ks) {
        const size_t k0 = (size_t)kc * 768 + ks * 32;
        #pragma unroll
        for (int r = 0; r < 6; ++r) {
            int row = rowl + 32 * r;
            float4 wv = *(const float4*)&lw[(size_t)(o0 + row) * 196608 + k0 + kk4 * 4];
            sW[(kk4 * 4 + 0) * 196 + row] = wv.x;
            sW[(kk4 * 4 + 1) * 196 + row] = wv.y;
            sW[(kk4 * 4 + 2) * 196 + row] = wv.z;
            sW[(kk4 * 4 + 3) * 196 + row] = wv.w;
        }
        #pragma unroll
        for (int r = 0; r < 2; ++r) {
            int bb = rowl + 32 * r;
            float4 av = *(const float4*)&hf[(size_t)bb * 196608 + k0 + kk4 * 4];
            sA[(kk4 * 4 + 0) * 68 + bb] = av.x;
            sA[(kk4 * 4 + 1) * 68 + bb] = av.y;
            sA[(kk4 * 4 + 2) * 68 + bb] = av.z;
            sA[(kk4 * 4 + 3) * 68 + bb] = av.w;
        }
        __syncthreads();
        for (int k = 0; k < 32; ++k) {
            float4 a = *(const float4*)&sA[k * 68 + b0];
            float4 w0 = *(const float4*)&sW[k * 196 + o_loc];
            float4 w1 = *(const float4*)&sW[k * 196 + o_loc + 4];
            float4 w2 = *(const float4*)&sW[k * 196 + o_loc + 8];
            float av[4] = {a.x, a.y, a.z, a.w};
            float wv[12] = {w0.x,w0.y,w0.z,w0.w,w1.x,w1.y,w1.z,w1.w,w2.x,w2.y,w2.z,w2.w};
            #pragma unroll
            for (int oo = 0; oo < 12; ++oo)
                #pragma unroll
                for (int bi = 0; bi < 4; ++bi)
                    acc[oo][bi] += wv[oo] * av[bi];
        }
        __syncthreads();
    }
    // store partials: part[bid][b][o_in_tile], float4 over o
    const size_t pbase = (size_t)blockIdx.x * 12288;
    #pragma unroll
    for (int bi = 0; bi < 4; ++bi) {
        float* p = &part[pbase + (size_t)(b0 + bi) * 192 + o_loc];
        *(float4*)&p[0] = make_float4(acc[0][bi], acc[1][bi], acc[2][bi], acc[3][bi]);
        *(float4*)&p[4] = make_float4(acc[4][bi], acc[5][bi], acc[6][bi], acc[7][bi]);
        *(float4*)&p[8] = make_float4(acc[8][bi], acc[9][bi], acc[10][bi], acc[11][bi]);
    }
}

// out[b][o] = lb[o] + sum_kc part[kc*4+ot][b][ol]
__global__ __launch_bounds__(256)
void reduce_kernel(const float* __restrict__ part, const float* __restrict__ lb,
                   float* __restrict__ outp)
{
    int idx = blockIdx.x * 256 + threadIdx.x;   // 0..49151
    int b = idx / 768, o = idx - b * 768;
    int ot = o / 192, ol = o - ot * 192;
    const float* p = part + (size_t)ot * 12288 + (size_t)b * 192 + ol;
    float s0 = 0.f, s1 = 0.f, s2 = 0.f, s3 = 0.f;
    for (int kc = 0; kc < 256; kc += 4) {
        s0 += p[(size_t)(kc + 0) * 49152];
        s1 += p[(size_t)(kc + 1) * 49152];
        s2 += p[(size_t)(kc + 2) * 49152];
        s3 += p[(size_t)(kc + 3) * 49152];
    }
    outp[idx] = lb[o] + ((s0 + s1) + (s2 + s3));
}

// ============================================================
extern "C" void kernel_launch(void* const* d_in, const int* in_sizes, int n_in,
                              void* d_out, int out_size, void* d_ws, size_t ws_size,
                              hipStream_t stream)
{
    const float* x     = (const float*)d_in[0];
    const float* wih   = (const float*)d_in[1];
    const float* whh   = (const float*)d_in[2];
    const float* bih   = (const float*)d_in[3];
    const float* bhh   = (const float*)d_in[4];
    const float* wq_w  = (const float*)d_in[5];
    const float* wq_b  = (const float*)d_in[6];
    const float* wk_w  = (const float*)d_in[7];
    const float* wk_b  = (const float*)d_in[8];
    const float* emb_w = (const float*)d_in[9];
    const float* emb_b = (const float*)d_in[10];
    const float* gcn_w[3] = {(const float*)d_in[11], (const float*)d_in[15], (const float*)d_in[19]};
    const float* gcn_b[3] = {(const float*)d_in[12], (const float*)d_in[16], (const float*)d_in[20]};
    const float* cv_w[3]  = {(const float*)d_in[13], (const float*)d_in[17], (const float*)d_in[21]};
    const float* cv_b[3]  = {(const float*)d_in[14], (const float*)d_in[18], (const float*)d_in[22]};
    const float* lw = (const float*)d_in[23];
    const float* lb = (const float*)d_in[24];

    float* out  = (float*)d_out;
    float* ws   = (float*)d_ws;
    float* enc  = ws + OFF_ENC;
    float* An   = ws + OFF_AN;
    float* bufA = ws + OFF_A;
    float* bufB = ws + OFF_B;
    float* wt   = ws + OFF_WT;

    prep_wt_kernel<<<240, 256, 0, stream>>>(cv_w[0], cv_w[1], cv_w[2], wt);
    gru_kernel<<<512, 256, 0, stream>>>(x, wih, whh, bih, bhh, enc);
    attn_kernel<<<64, 256, 0, stream>>>(enc, wq_w, wq_b, wk_w, wk_b, An);

    linagg_kernel<0><<<3072, 256, 0, stream>>>(nullptr, x, emb_w, emb_b,
                                               gcn_w[0], gcn_b[0], An, bufA);
    conv_kernel<3><<<2048, 256, 0, stream>>>(bufA, wt, cv_b[0], bufB);

    linagg_kernel<1><<<3072, 256, 0, stream>>>(bufB, x, emb_w, emb_b,
                                               gcn_w[1], gcn_b[1], An, bufA);
    conv_kernel<5><<<2048, 256, 0, stream>>>(bufA, wt + 12288, cv_b[1], bufB);

    linagg_kernel<1><<<3072, 256, 0, stream>>>(bufB, x, emb_w, emb_b,
                                               gcn_w[2], gcn_b[2], An, bufA);
    conv_kernel<7><<<2048, 256, 0, stream>>>(bufA, wt + 32768, cv_b[2], bufB);

    // final: partials into bufA (free after conv7), then reduce
    final_kernel<<<1024, 256, 0, stream>>>(bufB, lw, bufA);
    reduce_kernel<<<192, 256, 0, stream>>>(bufA, lb, out);
}